// Round 5
// baseline (245.345 us; speedup 1.0000x reference)
//
#include <hip/hip_runtime.h>
#include <math.h>

#define ZEPS  0.01f
#define ZMEAN 0.1307f
#define ZSIGMA 0.3081f

constexpr int D = 1024, H = 4096, O = 10;

using short8 = __attribute__((ext_vector_type(8))) short;
using f32x4  = __attribute__((ext_vector_type(4))) float;
typedef unsigned short ushort_t;

__device__ inline unsigned short f2bf(float x) {  // RNE fp32 -> bf16 bits
    unsigned int u = __float_as_uint(x);
    u += 0x7FFFu + ((u >> 16) & 1u);
    return (unsigned short)(u >> 16);
}
__device__ inline float bf2f(unsigned short h) {
    return __uint_as_float(((unsigned int)h) << 16);
}
__device__ inline unsigned int f2bf2(float a, float b) {  // RNE pair -> packed
    return (unsigned int)f2bf(a) | ((unsigned int)f2bf(b) << 16);
}

// async 16B/lane global->LDS (lds dest = wave-uniform base, lane offset = lane*16)
__device__ inline void gl_lds16(const void* g, void* l) {
    __builtin_amdgcn_global_load_lds(
        (const __attribute__((address_space(1))) unsigned int*)g,
        (__attribute__((address_space(3))) unsigned int*)l, 16, 0, 0);
}

__device__ inline float zval(float xv) {
    float up = fminf(xv + ZEPS, 1.f);
    float lo = fmaxf(xv - ZEPS, 0.f);
    return (up + lo - ZMEAN) / ZSIGMA;
}
__device__ inline float zdia(float xv) {
    return fminf(xv + ZEPS, 1.f) / ZSIGMA;
}

// ---------------------------------------------------------------------------
__device__ inline void relu_params(float v, float r, float& vout, float& aout, float& tout) {
    float u = v + r, l = v - r;
    float denom = u - l;
    float slope = u / (denom == 0.f ? 1.f : denom);
    float term = (1.f - slope) * u * 0.5f;
    bool dead = (u <= 0.f);
    bool crossing = (u > 0.f) && (l < 0.f);
    vout = dead ? 0.f : (crossing ? (slope * v + term) : v);
    aout = dead ? 0.f : (crossing ? slope : 1.f);
    tout = (!dead && crossing) ? term : 0.f;
}

// ---------------------------------------------------------------------------
// k_pre: blocks [0,1024): layer1 (v1 = W1@values+b1 ; r1 = |W1|@d ; ReLU-1)
//        block 1024:      zero r2acc + pbufR
__global__ __launch_bounds__(256) void k_pre(const float* __restrict__ W1, const float* __restrict__ b1,
                                             const float* __restrict__ x,
                                             float* __restrict__ v1p, float* __restrict__ a1,
                                             float* __restrict__ t1,
                                             float* __restrict__ r2acc, float* __restrict__ pbufR) {
    int b = blockIdx.x;
    if (b < 1024) {
        int wid = threadIdx.x >> 6, lane = threadIdx.x & 63;
        int i = b * 4 + wid;
        const float* row = W1 + (size_t)i * D;
        float sv = 0.f, sr = 0.f;
#pragma unroll
        for (int it = 0; it < 4; ++it) {
            int j = it * 256 + lane * 4;
            float4 w = *(const float4*)&row[j];
            float4 xx = *(const float4*)&x[j];
            sv += w.x * zval(xx.x) + w.y * zval(xx.y) + w.z * zval(xx.z) + w.w * zval(xx.w);
            sr += fabsf(w.x) * zdia(xx.x) + fabsf(w.y) * zdia(xx.y) +
                  fabsf(w.z) * zdia(xx.z) + fabsf(w.w) * zdia(xx.w);
        }
#pragma unroll
        for (int m = 1; m <= 32; m <<= 1) {
            sv += __shfl_xor(sv, m, 64);
            sr += __shfl_xor(sr, m, 64);
        }
        if (lane == 0) {
            float vo, ao, to;
            relu_params(sv + b1[i], sr, vo, ao, to);
            v1p[i] = vo; a1[i] = ao; t1[i] = to;
        }
    } else {
        for (int k = threadIdx.x; k < H; k += 256) r2acc[k] = 0.f;
        for (int k = threadIdx.x; k < O * D; k += 256) pbufR[k] = 0.f;
    }
}

// ---------------------------------------------------------------------------
// k_mid (both halves depend only on k_pre's layer1):
//   blocks [0,1024):    ONE W2 pass: W2bf = bf16(W2) AND fp32 dots
//                       v2raw = W2@v1p, t2raw = W2@t1
//   blocks [1024,5120): scaleT — W1sT[j][k] = bf16( a1[k]*W1[k][j]*d[j] )
__global__ __launch_bounds__(256) void k_mid(const float* __restrict__ W1, const float* __restrict__ a1,
                                             const float* __restrict__ x, ushort_t* __restrict__ W1sT,
                                             const float* __restrict__ W2, const float* __restrict__ v1p,
                                             const float* __restrict__ t1, ushort_t* __restrict__ W2bf,
                                             float* __restrict__ v2raw, float* __restrict__ t2raw) {
    int b = blockIdx.x;
    if (b < 1024) {
        int wid = threadIdx.x >> 6, lane = threadIdx.x & 63;
        int i = b * 4 + wid;
        const float* row = W2 + (size_t)i * H;
        ushort_t* orow = W2bf + (size_t)i * H;
        float sv = 0.f, st = 0.f;
#pragma unroll 2
        for (int it = 0; it < 8; ++it) {
            int j = it * 512 + lane * 8;
            float4 w0 = *(const float4*)&row[j];
            float4 w1 = *(const float4*)&row[j + 4];
            float4 v0 = *(const float4*)&v1p[j];
            float4 v1 = *(const float4*)&v1p[j + 4];
            float4 t0 = *(const float4*)&t1[j];
            float4 t1v = *(const float4*)&t1[j + 4];
            sv += w0.x * v0.x + w0.y * v0.y + w0.z * v0.z + w0.w * v0.w
                + w1.x * v1.x + w1.y * v1.y + w1.z * v1.z + w1.w * v1.w;
            st += w0.x * t0.x + w0.y * t0.y + w0.z * t0.z + w0.w * t0.w
                + w1.x * t1v.x + w1.y * t1v.y + w1.z * t1v.z + w1.w * t1v.w;
            uint4 o;
            o.x = f2bf2(w0.x, w0.y);
            o.y = f2bf2(w0.z, w0.w);
            o.z = f2bf2(w1.x, w1.y);
            o.w = f2bf2(w1.z, w1.w);
            *(uint4*)&orow[j] = o;
        }
#pragma unroll
        for (int m = 1; m <= 32; m <<= 1) {
            sv += __shfl_xor(sv, m, 64);
            st += __shfl_xor(st, m, 64);
        }
        if (lane == 0) { v2raw[i] = sv; t2raw[i] = st; }
    } else {
        __shared__ float tile[32][33];
        int bb = b - 1024;
        int j0 = (bb & 31) * 32, k0 = (bb >> 5) * 32;
        int r = threadIdx.x >> 3;
        int c = (threadIdx.x & 7) * 4;
        float4 w = *(const float4*)&W1[(size_t)(k0 + r) * D + j0 + c];
        float4 xx = *(const float4*)&x[j0 + c];
        float a = a1[k0 + r];
        tile[r][c + 0] = a * w.x * zdia(xx.x);
        tile[r][c + 1] = a * w.y * zdia(xx.y);
        tile[r][c + 2] = a * w.z * zdia(xx.z);
        tile[r][c + 3] = a * w.w * zdia(xx.w);
        __syncthreads();
        ushort4 o;
        o.x = f2bf(tile[c + 0][r]);
        o.y = f2bf(tile[c + 1][r]);
        o.z = f2bf(tile[c + 2][r]);
        o.w = f2bf(tile[c + 3][r]);
        *(ushort4*)&W1sT[(size_t)(j0 + r) * H + k0 + c] = o;
    }
}

// ---------------------------------------------------------------------------
// eps(bf16) = bf16(W2) @ W1sT^T, FULL K (no split). R4-proven structure:
// BM=128, BN=64, BK=64, 256 thr / 4 waves (2x2, 64x32 wave tile),
// double-buffered 48KB LDS -> 2 blocks/CU. Grid 512. XCD-chunked remap.
// Epilogue fuses the |eps| row-sum (bf16-rounded, matching what eps3a reads):
// shfl-reduce over the 16-lane col group, one atomicAdd per row-segment.
#define GBK 64
__global__ __launch_bounds__(256) void k_gemm_mfma(const ushort_t* __restrict__ A,
                                                   const ushort_t* __restrict__ B,
                                                   ushort_t* __restrict__ C,
                                                   float* __restrict__ r2acc) {
    const int N = D, K = H;
    __shared__ __align__(16) ushort_t As[2][128 * GBK];   // 2 x 16 KB
    __shared__ __align__(16) ushort_t Bs[2][64 * GBK];    // 2 x 8 KB
    int orig = blockIdx.x;
    int b = (orig & 7) * 64 + (orig >> 3);    // bijective: 64 contiguous per XCD
    int ym = b >> 4;            // 0..31  (4 M-panels per XCD)
    int xn = b & 15;            // 0..15  (all N-panels per XCD)
    int tid = threadIdx.x;
    int wave = tid >> 6, lane = tid & 63;
    int bm = ym * 128, bn = xn * 64;
    int wm = (wave >> 1) * 64, wn = (wave & 1) * 32;   // 2x2 wave grid, 64x32/wave

    int srow = lane >> 3, scp = (lane & 7) ^ srow;          // staging geometry
    int r15 = lane & 15, quad = lane >> 4, key = r15 & 7;   // read-side swizzle

    const int S = K / GBK;  // 64

    const ushort_t* Ab = A + (size_t)(bm + wave * 32 + srow) * K + scp * 8;
    const ushort_t* Bb = B + (size_t)(bn + wave * 16 + srow) * K + scp * 8;

    auto issue = [&](int t, int buf) {
#pragma unroll
        for (int g = 0; g < 4; ++g)
            gl_lds16(Ab + (size_t)(g * 8) * K + t * GBK, &As[buf][(wave * 32 + g * 8) * GBK]);
#pragma unroll
        for (int g = 0; g < 2; ++g)
            gl_lds16(Bb + (size_t)(g * 8) * K + t * GBK, &Bs[buf][(wave * 16 + g * 8) * GBK]);
    };

    f32x4 acc[4][2];
#pragma unroll
    for (int p = 0; p < 4; ++p)
#pragma unroll
        for (int q = 0; q < 2; ++q) acc[p][q] = (f32x4){0.f, 0.f, 0.f, 0.f};

    issue(0, 0);
    __syncthreads();   // compiler-inserted vmcnt(0) drains the DMA

    for (int t = 0; t < S; ++t) {
        int buf = t & 1, nbuf = buf ^ 1;
        if (t + 1 < S) issue(t + 1, nbuf);   // prefetch overlaps MFMA below
#pragma unroll
        for (int kk = 0; kk < 2; ++kk) {
            short8 af[4], bfr[2];
#pragma unroll
            for (int mt = 0; mt < 4; ++mt)
                af[mt] = *(const short8*)&As[buf][(wm + mt * 16 + r15) * GBK + (((kk * 4 + quad) ^ key)) * 8];
#pragma unroll
            for (int nt = 0; nt < 2; ++nt)
                bfr[nt] = *(const short8*)&Bs[buf][(wn + nt * 16 + r15) * GBK + (((kk * 4 + quad) ^ key)) * 8];
#pragma unroll
            for (int mt = 0; mt < 4; ++mt)
#pragma unroll
                for (int nt = 0; nt < 2; ++nt)
                    acc[mt][nt] = __builtin_amdgcn_mfma_f32_16x16x32_bf16(af[mt], bfr[nt], acc[mt][nt], 0, 0, 0);
        }
        __syncthreads();   // co-resident block hides the drain
    }

    // epilogue: bf16 store + fused row-sum of |eps|
    float rsum[4][4];
#pragma unroll
    for (int mt = 0; mt < 4; ++mt)
#pragma unroll
        for (int rg = 0; rg < 4; ++rg) rsum[mt][rg] = 0.f;
#pragma unroll
    for (int mt = 0; mt < 4; ++mt) {
        int gr = bm + wm + mt * 16 + quad * 4;
#pragma unroll
        for (int nt = 0; nt < 2; ++nt) {
            int gc = bn + wn + nt * 16 + r15;
            f32x4 a = acc[mt][nt];
#pragma unroll
            for (int rg = 0; rg < 4; ++rg) {
                ushort_t hb = f2bf(a[rg]);
                C[(size_t)(gr + rg) * N + gc] = hb;
                rsum[mt][rg] += fabsf(bf2f(hb));
            }
        }
    }
#pragma unroll
    for (int mt = 0; mt < 4; ++mt)
#pragma unroll
        for (int rg = 0; rg < 4; ++rg) {
            float v = rsum[mt][rg];
            v += __shfl_xor(v, 1, 64);
            v += __shfl_xor(v, 2, 64);
            v += __shfl_xor(v, 4, 64);
            v += __shfl_xor(v, 8, 64);
            if (r15 == 0)
                atomicAdd(&r2acc[bm + wm + mt * 16 + quad * 4 + rg], v);
        }
}

// ---------------------------------------------------------------------------
// eps3a with inline ReLU-2 params: per ib-slice, compute w3s[i][o] =
// W3[o][i]*a2[i] into LDS (a2 from r2acc/v2raw/t2raw), then
// pbufR[o][j] += sum_i w3s[i][o] * eps[i][j]   (eps bf16, single buffer)
__global__ __launch_bounds__(256) void k_eps3a(const ushort_t* __restrict__ e,
                                               const float* __restrict__ r2acc,
                                               const float* __restrict__ v2raw,
                                               const float* __restrict__ t2raw,
                                               const float* __restrict__ b2,
                                               const float* __restrict__ W3,
                                               float* __restrict__ pbufR) {
    int jb = blockIdx.x, ib = blockIdx.y;      // 16 x 32
    __shared__ float w3sm[128][O];             // 5 KB
    int i0b = ib * 128;
    if (threadIdx.x < 128) {
        int i = i0b + threadIdx.x;
        float te = t2raw[i];
        float vo, ao, to;
        relu_params(v2raw[i] + b2[i], r2acc[i] + fabsf(te), vo, ao, to);
#pragma unroll
        for (int o = 0; o < O; ++o) w3sm[threadIdx.x][o] = W3[(size_t)o * H + i] * ao;
    }
    __syncthreads();

    int jj = threadIdx.x & 15, s = threadIdx.x >> 4;
    int j = jb * 64 + jj * 4;
    int i0 = i0b + s * 8;
    float acc[4][O];
#pragma unroll
    for (int c = 0; c < 4; ++c)
#pragma unroll
        for (int o = 0; o < O; ++o) acc[c][o] = 0.f;
    for (int ii = 0; ii < 8; ++ii) {
        int i = i0 + ii;
        ushort4 a = *(const ushort4*)&e[(size_t)i * D + j];
        float e0 = bf2f(a.x), ee1 = bf2f(a.y);
        float ee2 = bf2f(a.z), ee3 = bf2f(a.w);
        const float* w = &w3sm[i - i0b][0];
#pragma unroll
        for (int o = 0; o < O; ++o) {
            float wo = w[o];
            acc[0][o] += wo * e0; acc[1][o] += wo * ee1;
            acc[2][o] += wo * ee2; acc[3][o] += wo * ee3;
        }
    }
    __shared__ float sm[16][64][O];  // 40 KB
#pragma unroll
    for (int c = 0; c < 4; ++c)
#pragma unroll
        for (int o = 0; o < O; ++o) sm[s][jj * 4 + c][o] = acc[c][o];
    __syncthreads();
    for (int idx = threadIdx.x; idx < 64 * O; idx += 256) {
        int col = idx / O, o = idx % O;
        float t = 0.f;
#pragma unroll
        for (int ss = 0; ss < 16; ++ss) t += sm[ss][col][o];
        atomicAdd(&pbufR[(size_t)o * D + jb * 64 + col], t);
    }
}

// ---------------------------------------------------------------------------
// final: inline ReLU-2 params; u/l from v3 +- (sum|eps3| + |W3@(a2*t2col)| + |W3@t2|)
__global__ __launch_bounds__(256) void k_final(const float* __restrict__ W3, const float* __restrict__ b3,
                                               const float* __restrict__ r2acc,
                                               const float* __restrict__ v2raw,
                                               const float* __restrict__ t2raw,
                                               const float* __restrict__ b2,
                                               const float* __restrict__ pbufR, float* __restrict__ out) {
    int o = blockIdx.x, tid = threadIdx.x;
    float s3 = 0.f;
    for (int j = tid; j < D; j += 256) s3 += fabsf(pbufR[(size_t)o * D + j]);
    const float* row = W3 + (size_t)o * H;
    float sv = 0.f, s1 = 0.f, s2 = 0.f;
    for (int i = tid; i < H; i += 256) {
        float w = row[i];
        float te = t2raw[i];
        float vo, ao, to;
        relu_params(v2raw[i] + b2[i], r2acc[i] + fabsf(te), vo, ao, to);
        sv += w * vo;
        s1 += w * ao * te;
        s2 += w * to;
    }
    __shared__ float ra[256], rb[256], rc[256], rd[256];
    ra[tid] = sv; rb[tid] = s1; rc[tid] = s2; rd[tid] = s3;
    __syncthreads();
    for (int off = 128; off; off >>= 1) {
        if (tid < off) {
            ra[tid] += ra[tid + off]; rb[tid] += rb[tid + off];
            rc[tid] += rc[tid + off]; rd[tid] += rd[tid + off];
        }
        __syncthreads();
    }
    if (tid == 0) {
        float v3 = ra[0] + b3[o];
        float rr = rd[0] + fabsf(rb[0]) + fabsf(rc[0]);
        out[o] = v3 + rr;       // u
        out[O + o] = v3 - rr;   // l
    }
}

// ---------------------------------------------------------------------------
extern "C" void kernel_launch(void* const* d_in, const int* in_sizes, int n_in,
                              void* d_out, int out_size, void* d_ws, size_t ws_size,
                              hipStream_t stream) {
    const float* x  = (const float*)d_in[0];
    const float* W1 = (const float*)d_in[1];
    const float* b1 = (const float*)d_in[2];
    const float* W2 = (const float*)d_in[3];
    const float* b2 = (const float*)d_in[4];
    const float* W3 = (const float*)d_in[5];
    const float* b3 = (const float*)d_in[6];
    float* out = (float*)d_out;

    float* p = (float*)d_ws;
    float* v1p    = p; p += H;
    float* a1     = p; p += H;
    float* t1     = p; p += H;
    float* v2raw  = p; p += H;
    float* t2raw  = p; p += H;
    float* r2acc  = p; p += H;
    float* pbufR  = p; p += O * D + 8;                        // 40 KB
    ushort_t* eps   = (ushort_t*)p;                           // 8 MB bf16 (full-K eps2)
    ushort_t* W1sT  = eps + (size_t)H * D;                    // 8 MB bf16
    ushort_t* W2bf  = W1sT + (size_t)H * D;                   // 32 MB bf16

    k_pre<<<1025, 256, 0, stream>>>(W1, b1, x, v1p, a1, t1, r2acc, pbufR);
    k_mid<<<5120, 256, 0, stream>>>(W1, a1, x, W1sT, W2, v1p, t1, W2bf, v2raw, t2raw);
    k_gemm_mfma<<<512, 256, 0, stream>>>(W2bf, W1sT, eps, r2acc);
    k_eps3a<<<dim3(D / 64, 32), 256, 0, stream>>>(eps, r2acc, v2raw, t2raw, b2, W3, pbufR);
    k_final<<<O, 256, 0, stream>>>(W3, b3, r2acc, v2raw, t2raw, b2, pbufR, out);
}

// Round 7
// 242.635 us; speedup vs baseline: 1.0112x; 1.0112x over previous
//
#include <hip/hip_runtime.h>
#include <math.h>

#define ZEPS  0.01f
#define ZMEAN 0.1307f
#define ZSIGMA 0.3081f

constexpr int D = 1024, H = 4096, O = 10;

using short8 = __attribute__((ext_vector_type(8))) short;
using us8    = __attribute__((ext_vector_type(8))) unsigned short;
using f32x4  = __attribute__((ext_vector_type(4))) float;
typedef unsigned short ushort_t;

__device__ inline unsigned short f2bf(float x) {  // RNE fp32 -> bf16 bits
    unsigned int u = __float_as_uint(x);
    u += 0x7FFFu + ((u >> 16) & 1u);
    return (unsigned short)(u >> 16);
}
__device__ inline float bf2f(unsigned short h) {
    return __uint_as_float(((unsigned int)h) << 16);
}
__device__ inline unsigned int f2bf2(float a, float b) {  // RNE pair -> packed
    return (unsigned int)f2bf(a) | ((unsigned int)f2bf(b) << 16);
}

// async 16B/lane global->LDS (lds dest = wave-uniform base, lane offset = lane*16)
__device__ inline void gl_lds16(const void* g, void* l) {
    __builtin_amdgcn_global_load_lds(
        (const __attribute__((address_space(1))) unsigned int*)g,
        (__attribute__((address_space(3))) unsigned int*)l, 16, 0, 0);
}

__device__ inline float zval(float xv) {
    float up = fminf(xv + ZEPS, 1.f);
    float lo = fmaxf(xv - ZEPS, 0.f);
    return (up + lo - ZMEAN) / ZSIGMA;
}
__device__ inline float zdia(float xv) {
    return fminf(xv + ZEPS, 1.f) / ZSIGMA;
}

// ---------------------------------------------------------------------------
__device__ inline void relu_params(float v, float r, float& vout, float& aout, float& tout) {
    float u = v + r, l = v - r;
    float denom = u - l;
    float slope = u / (denom == 0.f ? 1.f : denom);
    float term = (1.f - slope) * u * 0.5f;
    bool dead = (u <= 0.f);
    bool crossing = (u > 0.f) && (l < 0.f);
    vout = dead ? 0.f : (crossing ? (slope * v + term) : v);
    aout = dead ? 0.f : (crossing ? slope : 1.f);
    tout = (!dead && crossing) ? term : 0.f;
}

// ---------------------------------------------------------------------------
// k_pre: blocks [0,1024): layer1 (v1 = W1@values+b1 ; r1 = |W1|@d ; ReLU-1)
//        blocks [1024,1088): zero pbufP (32 x O x D)
__global__ __launch_bounds__(256) void k_pre(const float* __restrict__ W1, const float* __restrict__ b1,
                                             const float* __restrict__ x,
                                             float* __restrict__ v1p, float* __restrict__ a1,
                                             float* __restrict__ t1,
                                             float* __restrict__ pbufP) {
    int b = blockIdx.x;
    if (b < 1024) {
        int wid = threadIdx.x >> 6, lane = threadIdx.x & 63;
        int i = b * 4 + wid;
        const float* row = W1 + (size_t)i * D;
        float sv = 0.f, sr = 0.f;
#pragma unroll
        for (int it = 0; it < 4; ++it) {
            int j = it * 256 + lane * 4;
            float4 w = *(const float4*)&row[j];
            float4 xx = *(const float4*)&x[j];
            sv += w.x * zval(xx.x) + w.y * zval(xx.y) + w.z * zval(xx.z) + w.w * zval(xx.w);
            sr += fabsf(w.x) * zdia(xx.x) + fabsf(w.y) * zdia(xx.y) +
                  fabsf(w.z) * zdia(xx.z) + fabsf(w.w) * zdia(xx.w);
        }
#pragma unroll
        for (int m = 1; m <= 32; m <<= 1) {
            sv += __shfl_xor(sv, m, 64);
            sr += __shfl_xor(sr, m, 64);
        }
        if (lane == 0) {
            float vo, ao, to;
            relu_params(sv + b1[i], sr, vo, ao, to);
            v1p[i] = vo; a1[i] = ao; t1[i] = to;
        }
    } else {
        int zb = b - 1024;                       // 64 blocks x 5120 floats
        size_t base = (size_t)zb * 5120;
        for (int k = threadIdx.x; k < 5120; k += 256) pbufP[base + k] = 0.f;
    }
}

// ---------------------------------------------------------------------------
// k_mid (both halves depend only on k_pre's layer1):
//   blocks [0,1024):    ONE W2 pass: W2bf = bf16(W2) AND fp32 dots
//                       v2raw = W2@v1p, t2raw = W2@t1
//   blocks [1024,5120): scaleT — W1sT[j][k] = bf16( a1[k]*W1[k][j]*d[j] )
__global__ __launch_bounds__(256) void k_mid(const float* __restrict__ W1, const float* __restrict__ a1,
                                             const float* __restrict__ x, ushort_t* __restrict__ W1sT,
                                             const float* __restrict__ W2, const float* __restrict__ v1p,
                                             const float* __restrict__ t1, ushort_t* __restrict__ W2bf,
                                             float* __restrict__ v2raw, float* __restrict__ t2raw) {
    int b = blockIdx.x;
    if (b < 1024) {
        int wid = threadIdx.x >> 6, lane = threadIdx.x & 63;
        int i = b * 4 + wid;
        const float* row = W2 + (size_t)i * H;
        ushort_t* orow = W2bf + (size_t)i * H;
        float sv = 0.f, st = 0.f;
#pragma unroll 2
        for (int it = 0; it < 8; ++it) {
            int j = it * 512 + lane * 8;
            float4 w0 = *(const float4*)&row[j];
            float4 w1 = *(const float4*)&row[j + 4];
            float4 v0 = *(const float4*)&v1p[j];
            float4 v1 = *(const float4*)&v1p[j + 4];
            float4 t0 = *(const float4*)&t1[j];
            float4 t1v = *(const float4*)&t1[j + 4];
            sv += w0.x * v0.x + w0.y * v0.y + w0.z * v0.z + w0.w * v0.w
                + w1.x * v1.x + w1.y * v1.y + w1.z * v1.z + w1.w * v1.w;
            st += w0.x * t0.x + w0.y * t0.y + w0.z * t0.z + w0.w * t0.w
                + w1.x * t1v.x + w1.y * t1v.y + w1.z * t1v.z + w1.w * t1v.w;
            uint4 o;
            o.x = f2bf2(w0.x, w0.y);
            o.y = f2bf2(w0.z, w0.w);
            o.z = f2bf2(w1.x, w1.y);
            o.w = f2bf2(w1.z, w1.w);
            *(uint4*)&orow[j] = o;
        }
#pragma unroll
        for (int m = 1; m <= 32; m <<= 1) {
            sv += __shfl_xor(sv, m, 64);
            st += __shfl_xor(st, m, 64);
        }
        if (lane == 0) { v2raw[i] = sv; t2raw[i] = st; }
    } else {
        __shared__ float tile[32][33];
        int bb = b - 1024;
        int j0 = (bb & 31) * 32, k0 = (bb >> 5) * 32;
        int r = threadIdx.x >> 3;
        int c = (threadIdx.x & 7) * 4;
        float4 w = *(const float4*)&W1[(size_t)(k0 + r) * D + j0 + c];
        float4 xx = *(const float4*)&x[j0 + c];
        float a = a1[k0 + r];
        tile[r][c + 0] = a * w.x * zdia(xx.x);
        tile[r][c + 1] = a * w.y * zdia(xx.y);
        tile[r][c + 2] = a * w.z * zdia(xx.z);
        tile[r][c + 3] = a * w.w * zdia(xx.w);
        __syncthreads();
        ushort4 o;
        o.x = f2bf(tile[c + 0][r]);
        o.y = f2bf(tile[c + 1][r]);
        o.z = f2bf(tile[c + 2][r]);
        o.w = f2bf(tile[c + 3][r]);
        *(ushort4*)&W1sT[(size_t)(j0 + r) * H + k0 + c] = o;
    }
}

// ---------------------------------------------------------------------------
// eps2(bf16) = bf16(W2) @ W1sT^T, split-K=2.  R1-verified structure (61us):
// BM=BN=128, BK=64, 256 thr / 4 waves, dbuf 64KB LDS, xb = b&7 (N-tile/XCD).
#define GBK 64
__global__ __launch_bounds__(256) void k_gemm_mfma(const ushort_t* __restrict__ A,
                                                   const ushort_t* __restrict__ B,
                                                   ushort_t* __restrict__ C) {
    const int N = D, K = H;
    __shared__ __align__(16) ushort_t As[2][128 * GBK];   // 2 x 16 KB
    __shared__ __align__(16) ushort_t Bs[2][128 * GBK];   // 2 x 16 KB
    int b = blockIdx.x;
    int xb = b & 7;          // N-tile == XCD id (round-robin dispatch heuristic)
    int v = b >> 3;          // 0..63
    int z = v & 1;           // split-K half
    int y = v >> 1;          // 0..31 M-tile
    int tid = threadIdx.x;
    int wave = tid >> 6, lane = tid & 63;
    int bm = y * 128, bn = xb * 128;
    int kbeg = z * (K / 2);
    ushort_t* Cz = C + (size_t)z * ((size_t)H * D);
    int wm = (wave >> 1) * 64, wn = (wave & 1) * 64;

    int srow = lane >> 3, sc = lane & 7, scp = sc ^ srow;   // staging geometry
    int r15 = lane & 15, quad = lane >> 4, key = r15 & 7;   // read-side swizzle

    const int S = (K / 2) / GBK;  // 32

    auto issue = [&](int s, int buf) {
#pragma unroll
        for (int g = 0; g < 4; ++g) {
            int row = wave * 32 + g * 8;
            gl_lds16(&A[(size_t)(bm + row + srow) * K + kbeg + s * GBK + scp * 8],
                     &As[buf][row * GBK]);
            gl_lds16(&B[(size_t)(bn + row + srow) * K + kbeg + s * GBK + scp * 8],
                     &Bs[buf][row * GBK]);
        }
    };

    f32x4 acc[4][4];
#pragma unroll
    for (int p = 0; p < 4; ++p)
#pragma unroll
        for (int q = 0; q < 4; ++q) acc[p][q] = (f32x4){0.f, 0.f, 0.f, 0.f};

    issue(0, 0);
    __syncthreads();   // drains DMA (compiler emits vmcnt(0) before s_barrier)

    for (int s = 0; s < S; ++s) {
        int buf = s & 1, nbuf = buf ^ 1;
        if (s + 1 < S) issue(s + 1, nbuf);   // prefetch overlaps MFMA below
#pragma unroll
        for (int kk = 0; kk < 2; ++kk) {
            short8 af[4], bfr[4];
#pragma unroll
            for (int mt = 0; mt < 4; ++mt)
                af[mt] = *(const short8*)&As[buf][(wm + mt * 16 + r15) * GBK + (((kk * 4 + quad) ^ key)) * 8];
#pragma unroll
            for (int nt = 0; nt < 4; ++nt)
                bfr[nt] = *(const short8*)&Bs[buf][(wn + nt * 16 + r15) * GBK + (((kk * 4 + quad) ^ key)) * 8];
#pragma unroll
            for (int mt = 0; mt < 4; ++mt)
#pragma unroll
                for (int nt = 0; nt < 4; ++nt)
                    acc[mt][nt] = __builtin_amdgcn_mfma_f32_16x16x32_bf16(af[mt], bfr[nt], acc[mt][nt], 0, 0, 0);
        }
        __syncthreads();
    }

    // epilogue: C row = quad*4+reg, col = lane&15; bf16 store
#pragma unroll
    for (int mt = 0; mt < 4; ++mt) {
        int gr = bm + wm + mt * 16 + quad * 4;
#pragma unroll
        for (int nt = 0; nt < 4; ++nt) {
            int gc = bn + wn + nt * 16 + r15;
            Cz[(size_t)(gr + 0) * N + gc] = f2bf(acc[mt][nt][0]);
            Cz[(size_t)(gr + 1) * N + gc] = f2bf(acc[mt][nt][1]);
            Cz[(size_t)(gr + 2) * N + gc] = f2bf(acc[mt][nt][2]);
            Cz[(size_t)(gr + 3) * N + gc] = f2bf(acc[mt][nt][3]);
        }
    }
}

// ---------------------------------------------------------------------------
// k_epsfuse: fuses relu2 + eps3a. 256 blocks x 16 rows (full columns each).
// Phase A: per-wave row-sums of |e1+e2| -> relu-params -> v2p/a2/t2 + w3sm LDS.
// Phase B: each thread owns 4 cols; acc[c][o] += w3sm[i][o]*(e1+e2)[i][j];
//          atomicAdd into group buffer pbufP[b&31] (8-way contention).
__global__ __launch_bounds__(256) void k_epsfuse(const ushort_t* __restrict__ e1, const ushort_t* __restrict__ e2,
                                                 const float* __restrict__ v2raw, const float* __restrict__ t2raw,
                                                 const float* __restrict__ b2, const float* __restrict__ W3,
                                                 float* __restrict__ v2p, float* __restrict__ a2,
                                                 float* __restrict__ t2, float* __restrict__ pbufP) {
    __shared__ float w3sm[16][O];
    int b = blockIdx.x, tid = threadIdx.x;
    int wid = tid >> 6, lane = tid & 63;
    int i0 = b * 16;

    // Phase A: wave w handles local rows w*4 .. w*4+3
#pragma unroll
    for (int rr = 0; rr < 4; ++rr) {
        int il = wid * 4 + rr;
        int i = i0 + il;
        const ushort_t* p1 = &e1[(size_t)i * D + lane * 16];
        const ushort_t* p2 = &e2[(size_t)i * D + lane * 16];
        float s = 0.f;
#pragma unroll
        for (int q = 0; q < 2; ++q) {
            us8 u1 = *(const us8*)(p1 + q * 8);
            us8 u2 = *(const us8*)(p2 + q * 8);
#pragma unroll
            for (int e = 0; e < 8; ++e) s += fabsf(bf2f(u1[e]) + bf2f(u2[e]));
        }
#pragma unroll
        for (int m = 1; m <= 32; m <<= 1) s += __shfl_xor(s, m, 64);
        float te = t2raw[i];
        float vo, ao, to;
        relu_params(v2raw[i] + b2[i], s + fabsf(te), vo, ao, to);
        if (lane == 0) { v2p[i] = vo; a2[i] = ao; t2[i] = to; }
        if (lane < O) w3sm[il][lane] = W3[(size_t)lane * H + i] * ao;
    }
    __syncthreads();

    // Phase B: thread owns cols j..j+3 (e rows are L1/L2-hot from phase A)
    int j = tid * 4;
    float acc[4][O];
#pragma unroll
    for (int c = 0; c < 4; ++c)
#pragma unroll
        for (int o = 0; o < O; ++o) acc[c][o] = 0.f;
#pragma unroll 4
    for (int il = 0; il < 16; ++il) {
        int i = i0 + il;
        ushort4 a = *(const ushort4*)&e1[(size_t)i * D + j];
        ushort4 bb = *(const ushort4*)&e2[(size_t)i * D + j];
        float es0 = bf2f(a.x) + bf2f(bb.x), es1 = bf2f(a.y) + bf2f(bb.y);
        float es2 = bf2f(a.z) + bf2f(bb.z), es3 = bf2f(a.w) + bf2f(bb.w);
        const float* w = &w3sm[il][0];
#pragma unroll
        for (int o = 0; o < O; ++o) {
            float wo = w[o];
            acc[0][o] += wo * es0; acc[1][o] += wo * es1;
            acc[2][o] += wo * es2; acc[3][o] += wo * es3;
        }
    }
    float* pg = &pbufP[(size_t)(b & 31) * O * D];
#pragma unroll
    for (int o = 0; o < O; ++o)
#pragma unroll
        for (int c = 0; c < 4; ++c)
            atomicAdd(&pg[(size_t)o * D + j + c], acc[c][o]);
}

// ---------------------------------------------------------------------------
// final: u/l = v3 +- (sum_j|sum_g pbufP| + |W3@(a2*t2raw)| + |W3@t2|)
__global__ __launch_bounds__(256) void k_final(const float* __restrict__ W3, const float* __restrict__ b3,
                                               const float* __restrict__ v2p, const float* __restrict__ a2,
                                               const float* __restrict__ t2, const float* __restrict__ t2raw,
                                               const float* __restrict__ pbufP, float* __restrict__ out) {
    int o = blockIdx.x, tid = threadIdx.x;
    float s3 = 0.f;
    for (int j = tid; j < D; j += 256) {
        float t = 0.f;
#pragma unroll
        for (int g = 0; g < 32; ++g) t += pbufP[((size_t)g * O + o) * D + j];
        s3 += fabsf(t);
    }
    const float* row = W3 + (size_t)o * H;
    float sv = 0.f, s1 = 0.f, s2 = 0.f;
    for (int i = tid; i < H; i += 256) {
        float w = row[i];
        sv += w * v2p[i];
        s1 += w * a2[i] * t2raw[i];
        s2 += w * t2[i];
    }
    __shared__ float ra[256], rb[256], rc[256], rd[256];
    ra[tid] = sv; rb[tid] = s1; rc[tid] = s2; rd[tid] = s3;
    __syncthreads();
    for (int off = 128; off; off >>= 1) {
        if (tid < off) {
            ra[tid] += ra[tid + off]; rb[tid] += rb[tid + off];
            rc[tid] += rc[tid + off]; rd[tid] += rd[tid + off];
        }
        __syncthreads();
    }
    if (tid == 0) {
        float v3 = ra[0] + b3[o];
        float rr = rd[0] + fabsf(rb[0]) + fabsf(rc[0]);
        out[o] = v3 + rr;       // u
        out[O + o] = v3 - rr;   // l
    }
}

// ---------------------------------------------------------------------------
extern "C" void kernel_launch(void* const* d_in, const int* in_sizes, int n_in,
                              void* d_out, int out_size, void* d_ws, size_t ws_size,
                              hipStream_t stream) {
    const float* x  = (const float*)d_in[0];
    const float* W1 = (const float*)d_in[1];
    const float* b1 = (const float*)d_in[2];
    const float* W2 = (const float*)d_in[3];
    const float* b2 = (const float*)d_in[4];
    const float* W3 = (const float*)d_in[5];
    const float* b3 = (const float*)d_in[6];
    float* out = (float*)d_out;

    float* p = (float*)d_ws;
    float* v1p    = p; p += H;
    float* a1     = p; p += H;
    float* t1     = p; p += H;
    float* v2raw  = p; p += H;
    float* t2raw  = p; p += H;
    float* v2p    = p; p += H;
    float* a2     = p; p += H;
    float* t2     = p; p += H;
    float* pbufP  = p; p += 32 * O * D + 8;                   // 1.25 MB (32 groups)
    ushort_t* eps2  = (ushort_t*)p;                           // 2 x 8 MB bf16 (split-K halves)
    ushort_t* W1sT  = eps2 + (size_t)2 * H * D;               // 8 MB bf16
    ushort_t* W2bf  = W1sT + (size_t)H * D;                   // 32 MB bf16
    ushort_t* eps2b = eps2 + (size_t)H * D;

    k_pre<<<1088, 256, 0, stream>>>(W1, b1, x, v1p, a1, t1, pbufP);
    k_mid<<<5120, 256, 0, stream>>>(W1, a1, x, W1sT, W2, v1p, t1, W2bf, v2raw, t2raw);
    k_gemm_mfma<<<512, 256, 0, stream>>>(W2bf, W1sT, eps2);
    k_epsfuse<<<256, 256, 0, stream>>>(eps2, eps2b, v2raw, t2raw, b2, W3, v2p, a2, t2, pbufP);
    k_final<<<O, 256, 0, stream>>>(W3, b3, v2p, a2, t2, t2raw, pbufP, out);
}

// Round 8
// 235.511 us; speedup vs baseline: 1.0418x; 1.0303x over previous
//
#include <hip/hip_runtime.h>
#include <math.h>

#define ZEPS  0.01f
#define ZMEAN 0.1307f
#define ZSIGMA 0.3081f

constexpr int D = 1024, H = 4096, O = 10;

using short8 = __attribute__((ext_vector_type(8))) short;
using us8    = __attribute__((ext_vector_type(8))) unsigned short;
using f32x4  = __attribute__((ext_vector_type(4))) float;
typedef unsigned short ushort_t;

__device__ inline unsigned short f2bf(float x) {  // RNE fp32 -> bf16 bits
    unsigned int u = __float_as_uint(x);
    u += 0x7FFFu + ((u >> 16) & 1u);
    return (unsigned short)(u >> 16);
}
__device__ inline float bf2f(unsigned short h) {
    return __uint_as_float(((unsigned int)h) << 16);
}

// round-half-up fp32 pair -> packed bf16x2 (2 ops/elt)
__device__ inline unsigned int f2bf2_fast(float a, float b) {
    unsigned int ua = __float_as_uint(a) + 0x8000u;
    unsigned int ub = __float_as_uint(b) + 0x8000u;
    return (ua >> 16) | (ub & 0xFFFF0000u);
}

// async 16B/lane global->LDS (lds dest = base + lane*16, wave-uniform base)
__device__ inline void gl_lds16(const void* g, void* l) {
    __builtin_amdgcn_global_load_lds(
        (const __attribute__((address_space(1))) unsigned int*)g,
        (__attribute__((address_space(3))) unsigned int*)l, 16, 0, 0);
}

__device__ inline float zval(float xv) {
    float up = fminf(xv + ZEPS, 1.f);
    float lo = fmaxf(xv - ZEPS, 0.f);
    return (up + lo - ZMEAN) / ZSIGMA;
}
__device__ inline float zdia(float xv) {
    return fminf(xv + ZEPS, 1.f) / ZSIGMA;
}

// ---------------------------------------------------------------------------
__device__ inline void relu_params(float v, float r, float& vout, float& aout, float& tout) {
    float u = v + r, l = v - r;
    float denom = u - l;
    float slope = u / (denom == 0.f ? 1.f : denom);
    float term = (1.f - slope) * u * 0.5f;
    bool dead = (u <= 0.f);
    bool crossing = (u > 0.f) && (l < 0.f);
    vout = dead ? 0.f : (crossing ? (slope * v + term) : v);
    aout = dead ? 0.f : (crossing ? slope : 1.f);
    tout = (!dead && crossing) ? term : 0.f;
}

// ---------------------------------------------------------------------------
// wave-per-row: v1 = W1@values+b1 ; r1 = |W1| @ d ; ReLU-1 params
// blocks [1024,1088): zero pbufP (32 x O x D)
__global__ __launch_bounds__(256) void k_layer1(const float* __restrict__ W1, const float* __restrict__ b1,
                                                const float* __restrict__ x,
                                                float* __restrict__ v1p, float* __restrict__ a1,
                                                float* __restrict__ t1, float* __restrict__ pbufP) {
    int b = blockIdx.x;
    if (b >= 1024) {
        size_t base = (size_t)(b - 1024) * 5120;
        for (int k = threadIdx.x; k < 5120; k += 256) pbufP[base + k] = 0.f;
        return;
    }
    int wid = threadIdx.x >> 6, lane = threadIdx.x & 63;
    int i = b * 4 + wid;
    const float* row = W1 + (size_t)i * D;
    float sv = 0.f, sr = 0.f;
#pragma unroll
    for (int it = 0; it < 4; ++it) {
        int j = it * 256 + lane * 4;
        float4 w = *(const float4*)&row[j];
        float4 xx = *(const float4*)&x[j];
        sv += w.x * zval(xx.x) + w.y * zval(xx.y) + w.z * zval(xx.z) + w.w * zval(xx.w);
        sr += fabsf(w.x) * zdia(xx.x) + fabsf(w.y) * zdia(xx.y) +
              fabsf(w.z) * zdia(xx.z) + fabsf(w.w) * zdia(xx.w);
    }
#pragma unroll
    for (int m = 1; m <= 32; m <<= 1) {
        sv += __shfl_xor(sv, m, 64);
        sr += __shfl_xor(sr, m, 64);
    }
    if (lane == 0) {
        float vo, ao, to;
        relu_params(sv + b1[i], sr, vo, ao, to);
        v1p[i] = vo; a1[i] = ao; t1[i] = to;
    }
}

// W1sT[j][k] = bf16( a1[k] * W1[k][j] * d[j] )  — transposed, k-contiguous
__global__ __launch_bounds__(256) void k_scaleT(const float* __restrict__ W1, const float* __restrict__ a1,
                                                const float* __restrict__ x,
                                                ushort_t* __restrict__ W1sT) {
    __shared__ float tile[32][33];
    int j0 = blockIdx.x * 32, k0 = blockIdx.y * 32;
    int r = threadIdx.x >> 3;
    int c = (threadIdx.x & 7) * 4;
    float4 w = *(const float4*)&W1[(size_t)(k0 + r) * D + j0 + c];
    float4 xx = *(const float4*)&x[j0 + c];
    float a = a1[k0 + r];
    tile[r][c + 0] = a * w.x * zdia(xx.x);
    tile[r][c + 1] = a * w.y * zdia(xx.y);
    tile[r][c + 2] = a * w.z * zdia(xx.z);
    tile[r][c + 3] = a * w.w * zdia(xx.w);
    __syncthreads();
    ushort4 o;
    o.x = f2bf(tile[c + 0][r]);
    o.y = f2bf(tile[c + 1][r]);
    o.z = f2bf(tile[c + 2][r]);
    o.w = f2bf(tile[c + 3][r]);
    *(ushort4*)&W1sT[(size_t)(j0 + r) * H + k0 + c] = o;
}

// ---------------------------------------------------------------------------
// eps2(bf16) = bf16(W2) @ W1sT^T, split-K=2, XCD remap. Software-pipelined:
// double-buffered As/Bs, 1 barrier/iter. A staged fp32->regs (prefetched one
// step ahead, latency hidden under MFMA) -> cvt -> swizzled ds_write.
// v2/t2col partial dots from the fp32 A regs on steps (s&7)==xb.
// (Round-0 verified kernel: 83us, FETCH 50MB — fp32 A re-reads absorbed by L3.)
#define GBK 64
__global__ __launch_bounds__(256) void k_gemm_mfma(const float* __restrict__ A,
                                                   const ushort_t* __restrict__ B,
                                                   const float* __restrict__ v1p,
                                                   const float* __restrict__ t1,
                                                   ushort_t* __restrict__ C,
                                                   float* __restrict__ vpart,
                                                   float* __restrict__ tpart) {
    const int N = D, K = H;
    __shared__ __align__(16) ushort_t As[2][128 * GBK];   // 2 x 16 KB
    __shared__ __align__(16) ushort_t Bs[2][128 * GBK];   // 2 x 16 KB
    __shared__ float vt[2048], tt[2048];                  // 16 KB
    int b = blockIdx.x;
    int u = b & 7, v = b >> 3;
    int z = u >> 2;
    int y = (u & 3) * 8 + (v >> 3);
    int xb = v & 7;
    int tid = threadIdx.x;
    int wave = tid >> 6, lane = tid & 63;
    int bm = y * 128, bn = xb * 128;
    int kbeg = z * (K / 2);
    ushort_t* Cz = C + (size_t)z * ((size_t)H * D);
    int wm = (wave >> 1) * 64, wn = (wave & 1) * 64;

    int srow = lane >> 3, sc = lane & 7, scp = sc ^ srow;   // B staging geometry
    int r15 = lane & 15, quad = lane >> 4, key = r15 & 7;   // read-side swizzle
    int rowg = tid >> 3, ch = tid & 7;                      // A staging geometry
    int aswz = ch ^ (rowg & 7);

    const int S = (K / 2) / GBK;  // 32

    float4 pa[4][2];
    float sv[4] = {0.f, 0.f, 0.f, 0.f}, st[4] = {0.f, 0.f, 0.f, 0.f};

    auto issueA = [&](int s) {
#pragma unroll
        for (int g = 0; g < 4; ++g) {
            const float* ap = &A[(size_t)(bm + g * 32 + rowg) * K + kbeg + s * GBK + ch * 8];
            pa[g][0] = *(const float4*)ap;
            pa[g][1] = *(const float4*)(ap + 4);
        }
    };
    auto issueB = [&](int s, int buf) {
#pragma unroll
        for (int g = 0; g < 4; ++g) {
            int row = wave * 32 + g * 8;
            gl_lds16(&B[(size_t)(bn + row + srow) * K + kbeg + s * GBK + scp * 8], &Bs[buf][row * GBK]);
        }
    };
    auto cvtwrite = [&](int s, int buf) {
        if ((s & 7) == xb) {
            const float* vp = &vt[s * 64 + ch * 8];
            const float* tp = &tt[s * 64 + ch * 8];
            float4 v0 = *(const float4*)vp, v1 = *(const float4*)(vp + 4);
            float4 t0 = *(const float4*)tp, t1v = *(const float4*)(tp + 4);
#pragma unroll
            for (int g = 0; g < 4; ++g) {
                sv[g] += pa[g][0].x * v0.x + pa[g][0].y * v0.y + pa[g][0].z * v0.z + pa[g][0].w * v0.w
                       + pa[g][1].x * v1.x + pa[g][1].y * v1.y + pa[g][1].z * v1.z + pa[g][1].w * v1.w;
                st[g] += pa[g][0].x * t0.x + pa[g][0].y * t0.y + pa[g][0].z * t0.z + pa[g][0].w * t0.w
                       + pa[g][1].x * t1v.x + pa[g][1].y * t1v.y + pa[g][1].z * t1v.z + pa[g][1].w * t1v.w;
            }
        }
#pragma unroll
        for (int g = 0; g < 4; ++g) {
            uint4 hh;
            hh.x = f2bf2_fast(pa[g][0].x, pa[g][0].y);
            hh.y = f2bf2_fast(pa[g][0].z, pa[g][0].w);
            hh.z = f2bf2_fast(pa[g][1].x, pa[g][1].y);
            hh.w = f2bf2_fast(pa[g][1].z, pa[g][1].w);
            *(uint4*)&As[buf][(g * 32 + rowg) * GBK + aswz * 8] = hh;
        }
    };

    f32x4 acc[4][4];
#pragma unroll
    for (int p = 0; p < 4; ++p)
#pragma unroll
        for (int q = 0; q < 4; ++q) acc[p][q] = (f32x4){0.f, 0.f, 0.f, 0.f};

    // prologue
    issueA(0);
    issueB(0, 0);
    for (int idx = tid; idx < 512; idx += 256) {
        *(float4*)&vt[idx * 4] = *(const float4*)&v1p[kbeg + idx * 4];
        *(float4*)&tt[idx * 4] = *(const float4*)&t1[kbeg + idx * 4];
    }
    __syncthreads();          // vt/tt visible (also drains B(0) DMA — prologue only)
    cvtwrite(0, 0);
    __syncthreads();

    for (int s = 0; s < S; ++s) {
        int buf = s & 1, nbuf = buf ^ 1;
        if (s + 1 < S) {
            issueA(s + 1);
            issueB(s + 1, nbuf);
        }
#pragma unroll
        for (int kk = 0; kk < 2; ++kk) {
            short8 af[4], bf[4];
#pragma unroll
            for (int mt = 0; mt < 4; ++mt)
                af[mt] = *(const short8*)&As[buf][(wm + mt * 16 + r15) * GBK + (((kk * 4 + quad) ^ key)) * 8];
#pragma unroll
            for (int nt = 0; nt < 4; ++nt)
                bf[nt] = *(const short8*)&Bs[buf][(wn + nt * 16 + r15) * GBK + (((kk * 4 + quad) ^ key)) * 8];
#pragma unroll
            for (int mt = 0; mt < 4; ++mt)
#pragma unroll
                for (int nt = 0; nt < 4; ++nt)
                    acc[mt][nt] = __builtin_amdgcn_mfma_f32_16x16x32_bf16(af[mt], bf[nt], acc[mt][nt], 0, 0, 0);
        }
        if (s + 1 < S) cvtwrite(s + 1, nbuf);
        __syncthreads();
    }

    // epilogue: C row = quad*4+reg, col = lane&15; bf16 store
#pragma unroll
    for (int mt = 0; mt < 4; ++mt) {
        int gr = bm + wm + mt * 16 + quad * 4;
#pragma unroll
        for (int nt = 0; nt < 4; ++nt) {
            int gc = bn + wn + nt * 16 + r15;
            Cz[(size_t)(gr + 0) * N + gc] = f2bf(acc[mt][nt][0]);
            Cz[(size_t)(gr + 1) * N + gc] = f2bf(acc[mt][nt][1]);
            Cz[(size_t)(gr + 2) * N + gc] = f2bf(acc[mt][nt][2]);
            Cz[(size_t)(gr + 3) * N + gc] = f2bf(acc[mt][nt][3]);
        }
    }

    // dot partials: reduce across the 8 lanes sharing a row, store race-free
#pragma unroll
    for (int g = 0; g < 4; ++g) {
        float a = sv[g], bb = st[g];
        a += __shfl_xor(a, 1, 64); a += __shfl_xor(a, 2, 64); a += __shfl_xor(a, 4, 64);
        bb += __shfl_xor(bb, 1, 64); bb += __shfl_xor(bb, 2, 64); bb += __shfl_xor(bb, 4, 64);
        if (ch == 0) {
            int i = bm + g * 32 + rowg;
            vpart[(size_t)(z * 8 + xb) * H + i] = a;
            tpart[(size_t)(z * 8 + xb) * H + i] = bb;
        }
    }
}

// ---------------------------------------------------------------------------
// k_epsfuse: merges relu2 + eps3a. 256 blocks x 16 rows (full columns each).
// Phase A (round-0 relu2 math): rowsum |e1+e2| + vpart/tpart reduce ->
//   relu-params -> v2p/a2/t2/t2col + w3sm LDS.
// Phase B (round-7 proven): acc[c][o] += w3sm[i][o]*(e1+e2)[i][j] with the e
//   rows L1/L2-hot from phase A; atomicAdd into group buffer pbufP[b&31].
__global__ __launch_bounds__(256) void k_epsfuse(const ushort_t* __restrict__ e1, const ushort_t* __restrict__ e2,
                                                 const float* __restrict__ vpart, const float* __restrict__ tpart,
                                                 const float* __restrict__ b2, const float* __restrict__ W3,
                                                 float* __restrict__ v2p, float* __restrict__ a2,
                                                 float* __restrict__ t2, float* __restrict__ t2col,
                                                 float* __restrict__ pbufP) {
    __shared__ float w3sm[16][O];
    int b = blockIdx.x, tid = threadIdx.x;
    int wid = tid >> 6, lane = tid & 63;
    int i0 = b * 16;

    // Phase A: wave w handles local rows w*4 .. w*4+3
#pragma unroll
    for (int rr = 0; rr < 4; ++rr) {
        int il = wid * 4 + rr;
        int i = i0 + il;
        const ushort_t* p1 = &e1[(size_t)i * D + lane * 16];
        const ushort_t* p2 = &e2[(size_t)i * D + lane * 16];
        float s = 0.f;
#pragma unroll
        for (int q = 0; q < 2; ++q) {
            us8 u1 = *(const us8*)(p1 + q * 8);
            us8 u2 = *(const us8*)(p2 + q * 8);
#pragma unroll
            for (int e = 0; e < 8; ++e) s += fabsf(bf2f(u1[e]) + bf2f(u2[e]));
        }
        float ve = (lane < 16) ? vpart[(size_t)lane * H + i] : 0.f;
        float te = (lane < 16) ? tpart[(size_t)lane * H + i] : 0.f;
#pragma unroll
        for (int m = 1; m <= 32; m <<= 1) {
            s += __shfl_xor(s, m, 64);
            ve += __shfl_xor(ve, m, 64);
            te += __shfl_xor(te, m, 64);
        }
        float vo, ao, to;
        relu_params(ve + b2[i], s + fabsf(te), vo, ao, to);
        if (lane == 0) { v2p[i] = vo; a2[i] = ao; t2[i] = to; t2col[i] = te; }
        if (lane < O) w3sm[il][lane] = W3[(size_t)lane * H + i] * ao;
    }
    __syncthreads();

    // Phase B: thread owns cols j..j+3 (e rows are L1/L2-hot from phase A)
    int j = tid * 4;
    float acc[4][O];
#pragma unroll
    for (int c = 0; c < 4; ++c)
#pragma unroll
        for (int o = 0; o < O; ++o) acc[c][o] = 0.f;
#pragma unroll 4
    for (int il = 0; il < 16; ++il) {
        int i = i0 + il;
        ushort4 a = *(const ushort4*)&e1[(size_t)i * D + j];
        ushort4 bb = *(const ushort4*)&e2[(size_t)i * D + j];
        float es0 = bf2f(a.x) + bf2f(bb.x), es1 = bf2f(a.y) + bf2f(bb.y);
        float es2 = bf2f(a.z) + bf2f(bb.z), es3 = bf2f(a.w) + bf2f(bb.w);
        const float* w = &w3sm[il][0];
#pragma unroll
        for (int o = 0; o < O; ++o) {
            float wo = w[o];
            acc[0][o] += wo * es0; acc[1][o] += wo * es1;
            acc[2][o] += wo * es2; acc[3][o] += wo * es3;
        }
    }
    float* pg = &pbufP[(size_t)(b & 31) * O * D];
#pragma unroll
    for (int o = 0; o < O; ++o)
#pragma unroll
        for (int c = 0; c < 4; ++c)
            atomicAdd(&pg[(size_t)o * D + j + c], acc[c][o]);
}

// ---------------------------------------------------------------------------
// final: u/l = v3 +- (sum_j|sum_g pbufP| + |W3@(a2*t2col)| + |W3@t2|)
__global__ __launch_bounds__(256) void k_final(const float* __restrict__ W3, const float* __restrict__ b3,
                                               const float* __restrict__ v2p, const float* __restrict__ a2,
                                               const float* __restrict__ t2col, const float* __restrict__ t2,
                                               const float* __restrict__ pbufP, float* __restrict__ out) {
    int o = blockIdx.x, tid = threadIdx.x;
    float s3 = 0.f;
    for (int j = tid; j < D; j += 256) {
        float t = 0.f;
#pragma unroll
        for (int g = 0; g < 32; ++g) t += pbufP[((size_t)g * O + o) * D + j];
        s3 += fabsf(t);
    }
    const float* row = W3 + (size_t)o * H;
    float sv = 0.f, s1 = 0.f, s2 = 0.f;
    for (int i = tid; i < H; i += 256) {
        float w = row[i];
        sv += w * v2p[i];
        s1 += w * a2[i] * t2col[i];
        s2 += w * t2[i];
    }
    __shared__ float ra[256], rb[256], rc[256], rd[256];
    ra[tid] = sv; rb[tid] = s1; rc[tid] = s2; rd[tid] = s3;
    __syncthreads();
    for (int off = 128; off; off >>= 1) {
        if (tid < off) {
            ra[tid] += ra[tid + off]; rb[tid] += rb[tid + off];
            rc[tid] += rc[tid + off]; rd[tid] += rd[tid + off];
        }
        __syncthreads();
    }
    if (tid == 0) {
        float v3 = ra[0] + b3[o];
        float rr = rd[0] + fabsf(rb[0]) + fabsf(rc[0]);
        out[o] = v3 + rr;       // u
        out[O + o] = v3 - rr;   // l
    }
}

// ---------------------------------------------------------------------------
extern "C" void kernel_launch(void* const* d_in, const int* in_sizes, int n_in,
                              void* d_out, int out_size, void* d_ws, size_t ws_size,
                              hipStream_t stream) {
    const float* x  = (const float*)d_in[0];
    const float* W1 = (const float*)d_in[1];
    const float* b1 = (const float*)d_in[2];
    const float* W2 = (const float*)d_in[3];
    const float* b2 = (const float*)d_in[4];
    const float* W3 = (const float*)d_in[5];
    const float* b3 = (const float*)d_in[6];
    float* out = (float*)d_out;

    float* p = (float*)d_ws;
    float* v1p    = p; p += H;
    float* a1     = p; p += H;
    float* t1     = p; p += H;
    float* t2col  = p; p += H;
    float* v2p    = p; p += H;
    float* a2     = p; p += H;
    float* t2     = p; p += H;
    float* vpart  = p; p += 16 * H;
    float* tpart  = p; p += 16 * H;
    float* pbufP  = p; p += 32 * O * D + 8;                   // 1.25 MB (32 groups)
    ushort_t* eps2  = (ushort_t*)p;                           // 2 x 8 MB bf16 (split-K partials)
    ushort_t* W1sT  = eps2 + (size_t)2 * H * D;               // 8 MB bf16
    ushort_t* eps2b = eps2 + (size_t)H * D;

    k_layer1<<<1088, 256, 0, stream>>>(W1, b1, x, v1p, a1, t1, pbufP);
    k_scaleT<<<dim3(D / 32, H / 32), 256, 0, stream>>>(W1, a1, x, W1sT);
    k_gemm_mfma<<<512, 256, 0, stream>>>(W2, W1sT, v1p, t1, eps2, vpart, tpart);
    k_epsfuse<<<256, 256, 0, stream>>>(eps2, eps2b, vpart, tpart, b2, W3, v2p, a2, t2, t2col, pbufP);
    k_final<<<O, 256, 0, stream>>>(W3, b3, v2p, a2, t2col, t2, pbufP, out);
}